// Round 21
// baseline (79.350 us; speedup 1.0000x reference)
//
#include <hip/hip_runtime.h>
#include <math.h>

#define EPS 1e-6f

typedef _Float16 half8 __attribute__((ext_vector_type(8)));
typedef _Float16 half2v __attribute__((ext_vector_type(2)));
typedef __fp16  fp16x2r __attribute__((ext_vector_type(2)));
typedef float f32x16 __attribute__((ext_vector_type(16)));

__device__ __forceinline__ half2v cvt_pk(float a, float b) {
    fp16x2r v = __builtin_amdgcn_cvt_pkrtz(a, b);
    return __builtin_bit_cast(half2v, v);
}

__device__ __forceinline__ float fdot2f(half2v a, half2v b, float c) {
#if __has_builtin(__builtin_amdgcn_fdot2)
    return __builtin_amdgcn_fdot2(__builtin_bit_cast(fp16x2r, a),
                                  __builtin_bit_cast(fp16x2r, b), c, false);
#else
    return fmaf((float)a[0], (float)b[0], fmaf((float)a[1], (float)b[1], c));
#endif
}

// tanh poly finish for one 32x32 D-tile (transposed layout: lane = one g col).
__device__ __forceinline__ float tile_finish(const f32x16& D, uint4 va, uint4 vb,
                                             float yg) {
    const half2v CLO = {(_Float16)-2.5f, (_Float16)-2.5f};
    const half2v CHI = {(_Float16) 2.5f, (_Float16) 2.5f};
    const half2v C0  = {(_Float16)0.98335470f, (_Float16)0.98335470f};
    const half2v C1  = {(_Float16)-0.24780080f, (_Float16)-0.24780080f};
    const half2v C2  = {(_Float16)0.04040730f, (_Float16)0.04040730f};
    const half2v C3  = {(_Float16)-0.00252110f, (_Float16)-0.00252110f};
#define PAIR(jj, word) {                                          \
        half2v tt = cvt_pk(D[2*jj], D[2*jj+1]);                   \
        tt = __builtin_elementwise_max(tt, CLO);                  \
        tt = __builtin_elementwise_min(tt, CHI);                  \
        half2v u  = tt * tt;                                      \
        half2v pp = C3 * u + C2;                                  \
        pp = pp * u + C1;                                         \
        pp = pp * u + C0;                                         \
        half2v wt = tt * pp;                                      \
        yg = fdot2f(wt, __builtin_bit_cast(half2v, word), yg); }
    PAIR(0, va.x) PAIR(1, va.y) PAIR(2, va.z) PAIR(3, va.w)
    PAIR(4, vb.x) PAIR(5, vb.y) PAIR(6, vb.z) PAIR(7, vb.w)
#undef PAIR
    return yg;
}

// ---------------- Kernel 0: xh = (f16)x; zero xz1|xz2|hpre ------------------
// r21: 64 blocks (was 16 -> 240 CUs idle during the 2.1 MB zeroing).
__global__ __launch_bounds__(256) void k_xh(
    const float* __restrict__ x, _Float16* __restrict__ xh,
    float* __restrict__ zbuf) {
    const int tid = blockIdx.x * 256 + threadIdx.x;   // 0..16383
    if (tid < 4096) {
        const int i = tid * 8;
        float4 a = *(const float4*)(x + i);
        float4 b = *(const float4*)(x + i + 4);
        half8 o;
        o[0] = (_Float16)a.x; o[1] = (_Float16)a.y; o[2] = (_Float16)a.z; o[3] = (_Float16)a.w;
        o[4] = (_Float16)b.x; o[5] = (_Float16)b.y; o[6] = (_Float16)b.z; o[7] = (_Float16)b.w;
        *(half8*)(xh + i) = o;
    }
    const float4 z = {0.f, 0.f, 0.f, 0.f};
    for (int j = tid * 4; j < 557056; j += 16384 * 4)
        *(float4*)(zbuf + j) = z;
}

// ---------------- Kernel 1: fused GEMM [hpre|xz1|xz2] = xh @ [Wh|Wz1|Wz2] ---
// grid (136, 2, 2) x 128 threads: 64-col strips, K-half split, ROW-half split.
// Each output keeps exactly 2 atomic addends (k-halves) -> bitwise exact.
__global__ __launch_bounds__(128) void k_gemm(
    const _Float16* __restrict__ xh, const float* __restrict__ Wh,
    const float* __restrict__ Wz1, const float* __restrict__ Wz2,
    float* __restrict__ hpre, float* __restrict__ xz1,
    float* __restrict__ xz2) {
    const int s  = blockIdx.x;            // 64-col strip over [Wh|Wz1|Wz2]
    const int k0 = blockIdx.y * 256;
    const int r0 = blockIdx.z * 32;       // row half: 0-31 or 32-63
    const int t  = threadIdx.x;
    const int l  = t & 63, w = t >> 6;
    const int hi = l >> 5, l31 = l & 31;
    const int cbase = s * 64;

    const float* __restrict__ W;
    float* __restrict__ out;
    int ncols, ocol;
    if (s < 8)       { W = Wh;  out = hpre; ncols = 512;  ocol = cbase; }
    else if (s < 72) { W = Wz1; out = xz1;  ncols = 4096; ocol = cbase - 512; }
    else             { W = Wz2; out = xz2;  ncols = 4096; ocol = cbase - 4608; }

    const int col = ocol + 32 * w + l31;

    const f32x16 CZ = {0.f, 0.f, 0.f, 0.f, 0.f, 0.f, 0.f, 0.f,
                       0.f, 0.f, 0.f, 0.f, 0.f, 0.f, 0.f, 0.f};
    f32x16 acc0 = CZ;   // rows r0 .. r0+31

    const _Float16* __restrict__ a0p = xh + (r0 + l31) * 512 + 8 * hi + k0;
    const float* __restrict__    wp  = W + (size_t)(k0 + 8 * hi) * ncols + col;

#pragma unroll 2
    for (int kk = 0; kk < 256; kk += 16) {
        half8 a0 = *(const half8*)(a0p + kk);
        const float* wk = wp + (size_t)kk * ncols;
        half8 bf;
#pragma unroll
        for (int j = 0; j < 8; ++j)
            bf[j] = (_Float16)wk[(size_t)j * ncols];
        acc0 = __builtin_amdgcn_mfma_f32_32x32x16_f16(a0, bf, acc0, 0, 0, 0);
    }
#pragma unroll
    for (int i = 0; i < 16; ++i) {
        const int m = (i & 3) + 8 * (i >> 2) + 4 * hi;
        atomicAdd(out + (size_t)(r0 + m) * ncols + col, acc0[i]);
    }
}

// ---------------- Kernel 2: LayerNorm only (64 blocks) ----------------------
__global__ __launch_bounds__(256) void k_ln(
    const float* __restrict__ hpre, const float* __restrict__ bh,
    const float* __restrict__ ls, const float* __restrict__ lb,
    float* __restrict__ hout) {
    const int t = threadIdx.x;
    const int l = t & 63, wv = t >> 6;
    __shared__ float red[8];

    const int b = blockIdx.x;
    float h0 = fmaxf(hpre[b * 512 + t]       + bh[t],       0.f);
    float h1 = fmaxf(hpre[b * 512 + t + 256] + bh[t + 256], 0.f);
    float s = h0 + h1, ss = h0 * h0 + h1 * h1;
#pragma unroll
    for (int m = 1; m < 64; m <<= 1) {
        s  += __shfl_xor(s, m);
        ss += __shfl_xor(ss, m);
    }
    if (l == 0) { red[wv] = s; red[4 + wv] = ss; }
    __syncthreads();
    s  = red[0] + red[1] + red[2] + red[3];
    ss = red[4] + red[5] + red[6] + red[7];
    float mean = s * (1.0f / 512.0f);
    float var  = ss * (1.0f / 512.0f) - mean * mean;
    float rstd = rsqrtf(var + EPS);
    hout[b * 512 + t]       = (h0 - mean) * rstd * ls[t]       + lb[t];
    hout[b * 512 + t + 256] = (h1 - mean) * rstd * ls[t + 256] + lb[t + 256];
}

// ---------------- Kernel 3: FUSED prep + swapped-operand bilinear -----------
// 1024 blocks (one per row r). Prep (z f16, Gram stats, A-prescale, bias)
// lands in LDS -- no z1h/z2h global round-trip (was 33.6 MB of L2 traffic).
// Main loop = EXACT r14 shape (proven 47.96 us standalone): 4 B-tiles/wave,
// unroll 2, per-iter conditional addressing. Column g SPLIT across lane
// halves (r13): combine via shfl_xor(,32). q in-block, plain store.
__global__ __launch_bounds__(256) void k_fused(
    const float* __restrict__ xz1, const float* __restrict__ xz2,
    const float* __restrict__ Wz1, const float* __restrict__ Wz2,
    const float* __restrict__ hbuf,
    float* __restrict__ yout, float* __restrict__ qout) {
    const int r  = blockIdx.x;
    const int br = r >> 4, a = r & 15;
    const int t  = threadIdx.x;
    const int l  = t & 63, wv = t >> 6;
    const int hi = l >> 5, l31 = l & 31;

    __shared__ __align__(16) _Float16 z1t[513 * 8];   // [d][h]; row 512 = {1,0..}
    __shared__ __align__(16) _Float16 z2t[512 * 8];   // [g][h], A-prescaled
    __shared__ _Float16 bsh[512];                     // bias (f16)
    __shared__ __align__(16) unsigned int vp[256];    // packed v pairs, crow order
    __shared__ float red[44 * 4];
    __shared__ float Ssum[44];
    __shared__ float wq[4];

    // ---- stage v pairs + z1t pad row ----
    {
        const float* __restrict__ vrow = hbuf + br * 512;
        const int mm = t >> 4, h2 = (t >> 3) & 1, j = t & 7;
        const int d0 = mm * 32 + 2 * (j & 1) + 8 * (j >> 1) + 4 * h2;
        vp[t] = __builtin_bit_cast(unsigned int, cvt_pk(vrow[d0], vrow[d0 + 1]));
    }
    if (t == 0) {
        half8 one = {};
        one[0] = (_Float16)1.0f;
        *(half8*)(z1t + 512 * 8) = one;
    }

    // ---- prep phase 1: z1 -> LDS (f16), stats from f16-rounded z1 ----
    const float* __restrict__ x1  = xz1 + br * 4096;
    const float* __restrict__ x2  = xz2 + br * 4096;
    const float* __restrict__ w1r = Wz1 + (512 + a) * 4096;
    const float* __restrict__ w2r = Wz2 + (512 + a) * 4096;

    float pm[8], pg[36];
#pragma unroll
    for (int i = 0; i < 8; ++i) pm[i] = 0.f;
#pragma unroll
    for (int i = 0; i < 36; ++i) pg[i] = 0.f;

    half8 h2keep[2];
#pragma unroll
    for (int p = 0; p < 2; ++p) {
        const int d = t + p * 256;
        half8 h1, h2;
#pragma unroll
        for (int h = 0; h < 8; ++h) {
            float z1v = x1[h * 512 + d] + w1r[h * 512 + d];
            float z2v = x2[h * 512 + d] + w2r[h * 512 + d];
            h1[h] = (_Float16)z1v;
            h2[h] = (_Float16)z2v;
        }
        *(half8*)(z1t + d * 8) = h1;
        h2keep[p] = h2;
        float zr[8];
#pragma unroll
        for (int h = 0; h < 8; ++h) zr[h] = (float)h1[h];
#pragma unroll
        for (int h = 0; h < 8; ++h) pm[h] += zr[h];
        int id = 0;
#pragma unroll
        for (int h = 0; h < 8; ++h)
#pragma unroll
            for (int h2_ = h; h2_ < 8; ++h2_) { pg[id] += zr[h] * zr[h2_]; ++id; }
    }

#pragma unroll
    for (int m = 1; m < 64; m <<= 1) {
#pragma unroll
        for (int i = 0; i < 8; ++i)  pm[i] += __shfl_xor(pm[i], m);
#pragma unroll
        for (int i = 0; i < 36; ++i) pg[i] += __shfl_xor(pg[i], m);
    }
    if (l == 0) {
#pragma unroll
        for (int i = 0; i < 8; ++i)  red[i * 4 + wv]       = pm[i];
#pragma unroll
        for (int i = 0; i < 36; ++i) red[(8 + i) * 4 + wv] = pg[i];
    }
    __syncthreads();
    if (t < 44) Ssum[t] = red[t * 4 + 0] + red[t * 4 + 1] + red[t * 4 + 2] + red[t * 4 + 3];
    __syncthreads();

    // ---- prep phase 2: per-g scale/bias -> z2t (A-scaled) + bsh ----
#pragma unroll
    for (int p = 0; p < 2; ++p) {
        const int g = t + p * 256;
        float zv[8];
#pragma unroll
        for (int h = 0; h < 8; ++h) zv[h] = (float)h2keep[p][h];
        float mean = 0.f;
#pragma unroll
        for (int h = 0; h < 8; ++h) mean = fmaf(zv[h], Ssum[h], mean);
        mean *= (1.0f / 512.0f);
        float e2 = 0.f;
        int id = 0;
#pragma unroll
        for (int h = 0; h < 8; ++h)
#pragma unroll
            for (int h2_ = h; h2_ < 8; ++h2_) {
                float p2 = zv[h] * zv[h2_] * Ssum[8 + id];
                e2 += (h2_ == h) ? p2 : 2.0f * p2;
                ++id;
            }
        e2 *= (1.0f / 512.0f);
        float var  = e2 - mean * mean;
        float sd   = sqrtf(fmaxf(var, 0.f));
        float rstd = 1.0f / (sd + EPS);
        bsh[g] = (_Float16)(-mean * rstd);
        half8 hs;
#pragma unroll
        for (int h = 0; h < 8; ++h) hs[h] = (_Float16)(zv[h] * rstd);
        *(half8*)(z2t + g * 8) = hs;
    }
    __syncthreads();

    // ---- main loop (exact r14 shape): 4 B-tiles per wave ----
    const int gbl = wv * 128 + l31;
    half8 Bf0, Bf1, Bf2, Bf3;
    if (hi) {
        half8 z = {};
        Bf0 = z; Bf0[0] = bsh[gbl];
        Bf1 = z; Bf1[0] = bsh[gbl + 32];
        Bf2 = z; Bf2[0] = bsh[gbl + 64];
        Bf3 = z; Bf3[0] = bsh[gbl + 96];
    } else {
        Bf0 = *(const half8*)(z2t + gbl * 8);
        Bf1 = *(const half8*)(z2t + (gbl + 32) * 8);
        Bf2 = *(const half8*)(z2t + (gbl + 64) * 8);
        Bf3 = *(const half8*)(z2t + (gbl + 96) * 8);
    }

    const f32x16 CZ = {0.f, 0.f, 0.f, 0.f, 0.f, 0.f, 0.f, 0.f,
                       0.f, 0.f, 0.f, 0.f, 0.f, 0.f, 0.f, 0.f};
    float yg0 = 0.f, yg1 = 0.f, yg2 = 0.f, yg3 = 0.f;
#pragma unroll 2
    for (int m = 0; m < 16; ++m) {
        const int arow = hi ? 512 : (m * 32 + l31);
        const half8 Aa = *(const half8*)(z1t + arow * 8);
        const uint4 va = *(const uint4*)(vp + (m * 2 + hi) * 8);
        const uint4 vb = *(const uint4*)(vp + (m * 2 + hi) * 8 + 4);
        f32x16 D0 = __builtin_amdgcn_mfma_f32_32x32x16_f16(Aa, Bf0, CZ, 0, 0, 0);
        yg0 = tile_finish(D0, va, vb, yg0);
        f32x16 D1 = __builtin_amdgcn_mfma_f32_32x32x16_f16(Aa, Bf1, CZ, 0, 0, 0);
        yg1 = tile_finish(D1, va, vb, yg1);
        f32x16 D2 = __builtin_amdgcn_mfma_f32_32x32x16_f16(Aa, Bf2, CZ, 0, 0, 0);
        yg2 = tile_finish(D2, va, vb, yg2);
        f32x16 D3 = __builtin_amdgcn_mfma_f32_32x32x16_f16(Aa, Bf3, CZ, 0, 0, 0);
        yg3 = tile_finish(D3, va, vb, yg3);
    }

    // ---- combine the hi/lo half-sums of each g column (r13 fix) ----
    yg0 += __shfl_xor(yg0, 32);
    yg1 += __shfl_xor(yg1, 32);
    yg2 += __shfl_xor(yg2, 32);
    yg3 += __shfl_xor(yg3, 32);

    // ---- epilogue: y store from lo half; q in-block, plain store ----
    const int gy = r * 512 + wv * 128 + l31;
    if (!hi) {
        yout[gy]      = yg0;
        yout[gy + 32] = yg1;
        yout[gy + 64] = yg2;
        yout[gy + 96] = yg3;
    }
    float qacc = hi ? 0.f : (yg0 * yg0 + yg1 * yg1 + yg2 * yg2 + yg3 * yg3);
#pragma unroll
    for (int m = 1; m < 64; m <<= 1) qacc += __shfl_xor(qacc, m);
    if (l == 0) wq[wv] = qacc;
    __syncthreads();
    if (t == 0) qout[r] = (wq[0] + wq[1] + wq[2] + wq[3]) * (1.0f / 512.0f);
}

// ---------------------------------------------------------------------------
extern "C" void kernel_launch(void* const* d_in, const int* in_sizes, int n_in,
                              void* d_out, int out_size, void* d_ws, size_t ws_size,
                              hipStream_t stream) {
    const float* x   = (const float*)d_in[0];   // (64, 512)
    const float* Wh  = (const float*)d_in[1];   // (512, 512)
    const float* bh  = (const float*)d_in[2];   // (512,)
    const float* ls  = (const float*)d_in[3];   // (512,)
    const float* lb  = (const float*)d_in[4];   // (512,)
    const float* Wz1 = (const float*)d_in[5];   // (528, 4096)
    const float* Wz2 = (const float*)d_in[6];   // (528, 4096)

    float* out  = (float*)d_out;
    float* hout = out;                 // 64*512
    float* qout = out + 32768;         // 64*16
    float* yout = out + 33792;         // 1024*512

    // workspace layout (bytes); xz1|xz2|hpre contiguous (zeroed by k_xh)
    char* ws = (char*)d_ws;
    float*     xz1  = (float*)(ws);                           // 1 MB
    float*     xz2  = (float*)(ws + (1u << 20));              // 1 MB
    float*     hpre = (float*)(ws + (2u << 20));              // 128 KB
    _Float16*  xh   = (_Float16*)(ws + (2u << 20) + 135168);  // 64 KB

    k_xh   <<<64, 256, 0, stream>>>(x, xh, (float*)ws);
    k_gemm <<<dim3(136, 2, 2), 128, 0, stream>>>(xh, Wh, Wz1, Wz2, hpre, xz1, xz2);
    k_ln   <<<64, 256, 0, stream>>>(hpre, bh, ls, lb, hout);
    k_fused<<<1024, 256, 0, stream>>>(xz1, xz2, Wz1, Wz2, hout, yout, qout);
}

// Round 22
// 77.966 us; speedup vs baseline: 1.0178x; 1.0178x over previous
//
#include <hip/hip_runtime.h>
#include <math.h>

#define EPS 1e-6f

typedef _Float16 half8 __attribute__((ext_vector_type(8)));
typedef _Float16 half2v __attribute__((ext_vector_type(2)));
typedef __fp16  fp16x2r __attribute__((ext_vector_type(2)));
typedef float f32x16 __attribute__((ext_vector_type(16)));

__device__ __forceinline__ half2v cvt_pk(float a, float b) {
    fp16x2r v = __builtin_amdgcn_cvt_pkrtz(a, b);
    return __builtin_bit_cast(half2v, v);
}

__device__ __forceinline__ float fdot2f(half2v a, half2v b, float c) {
#if __has_builtin(__builtin_amdgcn_fdot2)
    return __builtin_amdgcn_fdot2(__builtin_bit_cast(fp16x2r, a),
                                  __builtin_bit_cast(fp16x2r, b), c, false);
#else
    return fmaf((float)a[0], (float)b[0], fmaf((float)a[1], (float)b[1], c));
#endif
}

// tanh poly finish for one 32x32 D-tile (transposed layout: lane = one g col).
__device__ __forceinline__ float tile_finish(const f32x16& D, uint4 va, uint4 vb,
                                             float yg) {
    const half2v CLO = {(_Float16)-2.5f, (_Float16)-2.5f};
    const half2v CHI = {(_Float16) 2.5f, (_Float16) 2.5f};
    const half2v C0  = {(_Float16)0.98335470f, (_Float16)0.98335470f};
    const half2v C1  = {(_Float16)-0.24780080f, (_Float16)-0.24780080f};
    const half2v C2  = {(_Float16)0.04040730f, (_Float16)0.04040730f};
    const half2v C3  = {(_Float16)-0.00252110f, (_Float16)-0.00252110f};
#define PAIR(jj, word) {                                          \
        half2v tt = cvt_pk(D[2*jj], D[2*jj+1]);                   \
        tt = __builtin_elementwise_max(tt, CLO);                  \
        tt = __builtin_elementwise_min(tt, CHI);                  \
        half2v u  = tt * tt;                                      \
        half2v pp = C3 * u + C2;                                  \
        pp = pp * u + C1;                                         \
        pp = pp * u + C0;                                         \
        half2v wt = tt * pp;                                      \
        yg = fdot2f(wt, __builtin_bit_cast(half2v, word), yg); }
    PAIR(0, va.x) PAIR(1, va.y) PAIR(2, va.z) PAIR(3, va.w)
    PAIR(4, vb.x) PAIR(5, vb.y) PAIR(6, vb.z) PAIR(7, vb.w)
#undef PAIR
    return yg;
}

// ---------------- Kernel 0: xh = (f16)x; zero xz1|xz2|hpre and qout ---------
__global__ __launch_bounds__(256) void k_xh(
    const float* __restrict__ x, _Float16* __restrict__ xh,
    float* __restrict__ zbuf, float* __restrict__ qout) {
    const int tid = blockIdx.x * 256 + threadIdx.x;
    const int i = tid * 8;
    float4 a = *(const float4*)(x + i);
    float4 b = *(const float4*)(x + i + 4);
    half8 o;
    o[0] = (_Float16)a.x; o[1] = (_Float16)a.y; o[2] = (_Float16)a.z; o[3] = (_Float16)a.w;
    o[4] = (_Float16)b.x; o[5] = (_Float16)b.y; o[6] = (_Float16)b.z; o[7] = (_Float16)b.w;
    *(half8*)(xh + i) = o;

    const float4 z = {0.f, 0.f, 0.f, 0.f};
#pragma unroll 2
    for (int j = tid * 4; j < 557056; j += 4096 * 4)
        *(float4*)(zbuf + j) = z;
    if (tid < 256) *(float4*)(qout + tid * 4) = z;   // qout: 1024 floats
}

// ---------------- Kernel 1: fused GEMM [hpre|xz1|xz2] = xh @ [Wh|Wz1|Wz2] ---
// grid (136, 2, 2) x 128 threads: 64-col strips, K-half split, ROW-half split.
// Each output keeps exactly 2 atomic addends (k-halves) -> bitwise exact.
__global__ __launch_bounds__(128) void k_gemm(
    const _Float16* __restrict__ xh, const float* __restrict__ Wh,
    const float* __restrict__ Wz1, const float* __restrict__ Wz2,
    float* __restrict__ hpre, float* __restrict__ xz1,
    float* __restrict__ xz2) {
    const int s  = blockIdx.x;            // 64-col strip over [Wh|Wz1|Wz2]
    const int k0 = blockIdx.y * 256;
    const int r0 = blockIdx.z * 32;       // row half: 0-31 or 32-63
    const int t  = threadIdx.x;
    const int l  = t & 63, w = t >> 6;
    const int hi = l >> 5, l31 = l & 31;
    const int cbase = s * 64;

    const float* __restrict__ W;
    float* __restrict__ out;
    int ncols, ocol;
    if (s < 8)       { W = Wh;  out = hpre; ncols = 512;  ocol = cbase; }
    else if (s < 72) { W = Wz1; out = xz1;  ncols = 4096; ocol = cbase - 512; }
    else             { W = Wz2; out = xz2;  ncols = 4096; ocol = cbase - 4608; }

    const int col = ocol + 32 * w + l31;

    const f32x16 CZ = {0.f, 0.f, 0.f, 0.f, 0.f, 0.f, 0.f, 0.f,
                       0.f, 0.f, 0.f, 0.f, 0.f, 0.f, 0.f, 0.f};
    f32x16 acc0 = CZ;   // rows r0 .. r0+31

    const _Float16* __restrict__ a0p = xh + (r0 + l31) * 512 + 8 * hi + k0;
    const float* __restrict__    wp  = W + (size_t)(k0 + 8 * hi) * ncols + col;

#pragma unroll 2
    for (int kk = 0; kk < 256; kk += 16) {
        half8 a0 = *(const half8*)(a0p + kk);
        const float* wk = wp + (size_t)kk * ncols;
        half8 bf;
#pragma unroll
        for (int j = 0; j < 8; ++j)
            bf[j] = (_Float16)wk[(size_t)j * ncols];
        acc0 = __builtin_amdgcn_mfma_f32_32x32x16_f16(a0, bf, acc0, 0, 0, 0);
    }
#pragma unroll
    for (int i = 0; i < 16; ++i) {
        const int m = (i & 3) + 8 * (i >> 2) + 4 * hi;
        atomicAdd(out + (size_t)(r0 + m) * ncols + col, acc0[i]);
    }
}

// ---------------- Kernel 2: fused LN (blocks 0-63) + prep (blocks 64-1087) --
__global__ __launch_bounds__(256) void k_mid(
    const float* __restrict__ hpre, const float* __restrict__ bh,
    const float* __restrict__ ls, const float* __restrict__ lb,
    const float* __restrict__ xz1, const float* __restrict__ xz2,
    const float* __restrict__ Wz1, const float* __restrict__ Wz2,
    float* __restrict__ hout,
    _Float16* __restrict__ z1h, _Float16* __restrict__ z2h,
    _Float16* __restrict__ z2bh) {
    const int t  = threadIdx.x;
    const int l  = t & 63, wv = t >> 6;

    __shared__ float red[44 * 4];
    __shared__ float Ssum[44];

    if (blockIdx.x < 64) {
        // ---------------- LayerNorm path ----------------
        const int b = blockIdx.x;
        float h0 = fmaxf(hpre[b * 512 + t]       + bh[t],       0.f);
        float h1 = fmaxf(hpre[b * 512 + t + 256] + bh[t + 256], 0.f);
        float s = h0 + h1, ss = h0 * h0 + h1 * h1;
#pragma unroll
        for (int m = 1; m < 64; m <<= 1) {
            s  += __shfl_xor(s, m);
            ss += __shfl_xor(ss, m);
        }
        if (l == 0) { red[wv] = s; red[4 + wv] = ss; }
        __syncthreads();
        s  = red[0] + red[1] + red[2] + red[3];
        ss = red[4] + red[5] + red[6] + red[7];
        float mean = s * (1.0f / 512.0f);
        float var  = ss * (1.0f / 512.0f) - mean * mean;
        float rstd = rsqrtf(var + EPS);
        hout[b * 512 + t]       = (h0 - mean) * rstd * ls[t]       + lb[t];
        hout[b * 512 + t + 256] = (h1 - mean) * rstd * ls[t + 256] + lb[t + 256];
        return;
    }

    // ---------------- prep path: one block per row r ----------------
    const int r  = blockIdx.x - 64;
    const int br = r >> 4, a = r & 15;

    const float* __restrict__ x1  = xz1 + br * 4096;
    const float* __restrict__ x2  = xz2 + br * 4096;
    const float* __restrict__ w1r = Wz1 + (512 + a) * 4096;
    const float* __restrict__ w2r = Wz2 + (512 + a) * 4096;

    float pm[8], pg[36];
#pragma unroll
    for (int i = 0; i < 8; ++i) pm[i] = 0.f;
#pragma unroll
    for (int i = 0; i < 36; ++i) pg[i] = 0.f;

    half8 h2keep[2];
#pragma unroll
    for (int p = 0; p < 2; ++p) {
        const int d = t + p * 256;
        half8 h1, h2;
#pragma unroll
        for (int h = 0; h < 8; ++h) {
            float z1v = x1[h * 512 + d] + w1r[h * 512 + d];
            float z2v = x2[h * 512 + d] + w2r[h * 512 + d];
            h1[h] = (_Float16)z1v;
            h2[h] = (_Float16)z2v;
        }
        *(half8*)(z1h + ((size_t)r * 512 + d) * 8) = h1;
        h2keep[p] = h2;
        float zr[8];
#pragma unroll
        for (int h = 0; h < 8; ++h) zr[h] = (float)h1[h];
#pragma unroll
        for (int h = 0; h < 8; ++h) pm[h] += zr[h];
        int id = 0;
#pragma unroll
        for (int h = 0; h < 8; ++h)
#pragma unroll
            for (int h2_ = h; h2_ < 8; ++h2_) { pg[id] += zr[h] * zr[h2_]; ++id; }
    }

#pragma unroll
    for (int m = 1; m < 64; m <<= 1) {
#pragma unroll
        for (int i = 0; i < 8; ++i)  pm[i] += __shfl_xor(pm[i], m);
#pragma unroll
        for (int i = 0; i < 36; ++i) pg[i] += __shfl_xor(pg[i], m);
    }
    if (l == 0) {
#pragma unroll
        for (int i = 0; i < 8; ++i)  red[i * 4 + wv]       = pm[i];
#pragma unroll
        for (int i = 0; i < 36; ++i) red[(8 + i) * 4 + wv] = pg[i];
    }
    __syncthreads();
    if (t < 44) Ssum[t] = red[t * 4 + 0] + red[t * 4 + 1] + red[t * 4 + 2] + red[t * 4 + 3];
    __syncthreads();

#pragma unroll
    for (int p = 0; p < 2; ++p) {
        const int g = t + p * 256;
        float zv[8];
#pragma unroll
        for (int h = 0; h < 8; ++h) zv[h] = (float)h2keep[p][h];
        float mean = 0.f;
#pragma unroll
        for (int h = 0; h < 8; ++h) mean = fmaf(zv[h], Ssum[h], mean);
        mean *= (1.0f / 512.0f);
        float e2 = 0.f;
        int id = 0;
#pragma unroll
        for (int h = 0; h < 8; ++h)
#pragma unroll
            for (int h2_ = h; h2_ < 8; ++h2_) {
                float p2 = zv[h] * zv[h2_] * Ssum[8 + id];
                e2 += (h2_ == h) ? p2 : 2.0f * p2;
                ++id;
            }
        e2 *= (1.0f / 512.0f);
        float var  = e2 - mean * mean;
        float sd   = sqrtf(fmaxf(var, 0.f));
        float rstd = 1.0f / (sd + EPS);
        z2bh[r * 512 + g] = (_Float16)(-mean * rstd);   // bias (no scale factor)
        half8 hs;
#pragma unroll
        for (int h = 0; h < 8; ++h) hs[h] = (_Float16)(zv[h] * rstd);
        *(half8*)(z2h + ((size_t)r * 512 + g) * 8) = hs;
    }
}

// ---------------- Kernel 3: SWAPPED-operand MFMA bilinear + lane-local dot --
// EXACT r15/r18 shape (proven 47.4 us, VGPR=40, WRITE 2.1 MB). Failed
// perturbations: r9 (reg-array scratch), r11 (launch_bounds 8 spill),
// r16 (hoist/full-unroll remat), r19 (unroll 4 spill), r21 (prep fusion:
// occupancy loss > traffic gain). unroll 2 + per-iter conditional addressing
// at 2048 blocks is the verified optimum. FROZEN.
__global__ __launch_bounds__(256, 4) void k_main(
    const _Float16* __restrict__ z1h, const _Float16* __restrict__ z2h,
    const _Float16* __restrict__ z2bh, const float* __restrict__ hbuf,
    float* __restrict__ yout, float* __restrict__ qout) {
    const int bx = blockIdx.x;
    const int r  = bx >> 1, gh = bx & 1;
    const int br = r >> 4;
    const int t  = threadIdx.x;
    const int l  = t & 63, wv = t >> 6;
    const int hi = l >> 5, l31 = l & 31;

    __shared__ __align__(16) _Float16 z1t[513 * 8];   // [d][h]; row 512 = {1,0..}
    __shared__ __align__(16) unsigned int vp[256];    // packed (v[d0],v[d0+1]) crow order
    __shared__ float wq[4];

    // ---- stage z1 ----
#pragma unroll
    for (int p = 0; p < 2; ++p) {
        const int d = t + p * 256;
        *(half8*)(z1t + d * 8) = *(const half8*)(z1h + ((size_t)r * 512 + d) * 8);
    }
    if (t == 0) {
        half8 one = {};
        one[0] = (_Float16)1.0f;
        *(half8*)(z1t + 512 * 8) = one;
    }
    // ---- stage v pairs in crow order: vp[(m*2+h2)*8 + j] ----
    {
        const float* __restrict__ vrow = hbuf + br * 512;
        const int mm = t >> 4, h2 = (t >> 3) & 1, j = t & 7;
        const int d0 = mm * 32 + 2 * (j & 1) + 8 * (j >> 1) + 4 * h2;
        vp[t] = __builtin_bit_cast(unsigned int, cvt_pk(vrow[d0], vrow[d0 + 1]));
    }
    __syncthreads();

    // ---- B fragments: 2 n-tiles per wave (g = gh*256 + wv*64 + {0,32}) ----
    const size_t gb = (size_t)r * 512 + gh * 256 + wv * 64 + l31;
    half8 Bf0, Bf1;
    if (hi) {
        half8 z = {};
        Bf0 = z; Bf0[0] = z2bh[gb];
        Bf1 = z; Bf1[0] = z2bh[gb + 32];
    } else {
        Bf0 = *(const half8*)(z2h + gb * 8);
        Bf1 = *(const half8*)(z2h + (gb + 32) * 8);
    }

    const f32x16 CZ = {0.f, 0.f, 0.f, 0.f, 0.f, 0.f, 0.f, 0.f,
                       0.f, 0.f, 0.f, 0.f, 0.f, 0.f, 0.f, 0.f};
    float yg0 = 0.f, yg1 = 0.f;
#pragma unroll 2
    for (int m = 0; m < 16; ++m) {
        const int arow = hi ? 512 : (m * 32 + l31);
        const half8 Aa = *(const half8*)(z1t + arow * 8);
        const uint4 va = *(const uint4*)(vp + (m * 2 + hi) * 8);
        const uint4 vb = *(const uint4*)(vp + (m * 2 + hi) * 8 + 4);
        f32x16 D0 = __builtin_amdgcn_mfma_f32_32x32x16_f16(Aa, Bf0, CZ, 0, 0, 0);
        yg0 = tile_finish(D0, va, vb, yg0);
        f32x16 D1 = __builtin_amdgcn_mfma_f32_32x32x16_f16(Aa, Bf1, CZ, 0, 0, 0);
        yg1 = tile_finish(D1, va, vb, yg1);
    }

    // ---- combine the hi/lo half-sums of each g column (r13 fix) ----
    yg0 += __shfl_xor(yg0, 32);
    yg1 += __shfl_xor(yg1, 32);

    // ---- epilogue: y store from lo half; q via 2-addend atomicAdd ----
    const int gy = r * 512 + gh * 256 + wv * 64 + l31;
    if (!hi) {
        yout[gy]      = yg0;
        yout[gy + 32] = yg1;
    }
    float qacc = hi ? 0.f : (yg0 * yg0 + yg1 * yg1);
#pragma unroll
    for (int m = 1; m < 64; m <<= 1) qacc += __shfl_xor(qacc, m);
    if (l == 0) wq[wv] = qacc;
    __syncthreads();
    if (t == 0) atomicAdd(qout + r, (wq[0] + wq[1] + wq[2] + wq[3]) * (1.0f / 512.0f));
}

// ---------------------------------------------------------------------------
extern "C" void kernel_launch(void* const* d_in, const int* in_sizes, int n_in,
                              void* d_out, int out_size, void* d_ws, size_t ws_size,
                              hipStream_t stream) {
    const float* x   = (const float*)d_in[0];   // (64, 512)
    const float* Wh  = (const float*)d_in[1];   // (512, 512)
    const float* bh  = (const float*)d_in[2];   // (512,)
    const float* ls  = (const float*)d_in[3];   // (512,)
    const float* lb  = (const float*)d_in[4];   // (512,)
    const float* Wz1 = (const float*)d_in[5];   // (528, 4096)
    const float* Wz2 = (const float*)d_in[6];   // (528, 4096)

    float* out  = (float*)d_out;
    float* hout = out;                 // 64*512
    float* qout = out + 32768;         // 64*16
    float* yout = out + 33792;         // 1024*512

    // workspace layout (bytes); xz1|xz2|hpre contiguous (zeroed by k_xh)
    char* ws = (char*)d_ws;
    float*     xz1  = (float*)(ws);                           // 1 MB
    float*     xz2  = (float*)(ws + (1u << 20));              // 1 MB
    float*     hpre = (float*)(ws + (2u << 20));              // 128 KB
    _Float16*  xh   = (_Float16*)(ws + (2u << 20) + 135168);  // 64 KB
    _Float16*  z2bh = (_Float16*)(ws + (2u << 20) + 200704);  // 1 MB
    _Float16*  z1h  = (_Float16*)(ws + (4u << 20));           // 8.4 MB
    _Float16*  z2h  = z1h + (size_t)1024 * 512 * 8;           // 8.4 MB

    k_xh  <<<16, 256, 0, stream>>>(x, xh, (float*)ws, qout);
    k_gemm<<<dim3(136, 2, 2), 128, 0, stream>>>(xh, Wh, Wz1, Wz2, hpre, xz1, xz2);
    k_mid <<<1088, 256, 0, stream>>>(hpre, bh, ls, lb, xz1, xz2, Wz1, Wz2,
                                     hout, z1h, z2h, z2bh);
    k_main<<<2048, 256, 0, stream>>>(z1h, z2h, z2bh, hout, yout, qout);
}

// Round 23
// 76.973 us; speedup vs baseline: 1.0309x; 1.0129x over previous
//
#include <hip/hip_runtime.h>
#include <math.h>

#define EPS 1e-6f

typedef _Float16 half8 __attribute__((ext_vector_type(8)));
typedef _Float16 half2v __attribute__((ext_vector_type(2)));
typedef __fp16  fp16x2r __attribute__((ext_vector_type(2)));
typedef float f32x16 __attribute__((ext_vector_type(16)));

__device__ __forceinline__ half2v cvt_pk(float a, float b) {
    fp16x2r v = __builtin_amdgcn_cvt_pkrtz(a, b);
    return __builtin_bit_cast(half2v, v);
}

__device__ __forceinline__ float fdot2f(half2v a, half2v b, float c) {
#if __has_builtin(__builtin_amdgcn_fdot2)
    return __builtin_amdgcn_fdot2(__builtin_bit_cast(fp16x2r, a),
                                  __builtin_bit_cast(fp16x2r, b), c, false);
#else
    return fmaf((float)a[0], (float)b[0], fmaf((float)a[1], (float)b[1], c));
#endif
}

// tanh poly finish for one 32x32 D-tile (transposed layout: lane = one g col).
__device__ __forceinline__ float tile_finish(const f32x16& D, uint4 va, uint4 vb,
                                             float yg) {
    const half2v CLO = {(_Float16)-2.5f, (_Float16)-2.5f};
    const half2v CHI = {(_Float16) 2.5f, (_Float16) 2.5f};
    const half2v C0  = {(_Float16)0.98335470f, (_Float16)0.98335470f};
    const half2v C1  = {(_Float16)-0.24780080f, (_Float16)-0.24780080f};
    const half2v C2  = {(_Float16)0.04040730f, (_Float16)0.04040730f};
    const half2v C3  = {(_Float16)-0.00252110f, (_Float16)-0.00252110f};
#define PAIR(jj, word) {                                          \
        half2v tt = cvt_pk(D[2*jj], D[2*jj+1]);                   \
        tt = __builtin_elementwise_max(tt, CLO);                  \
        tt = __builtin_elementwise_min(tt, CHI);                  \
        half2v u  = tt * tt;                                      \
        half2v pp = C3 * u + C2;                                  \
        pp = pp * u + C1;                                         \
        pp = pp * u + C0;                                         \
        half2v wt = tt * pp;                                      \
        yg = fdot2f(wt, __builtin_bit_cast(half2v, word), yg); }
    PAIR(0, va.x) PAIR(1, va.y) PAIR(2, va.z) PAIR(3, va.w)
    PAIR(4, vb.x) PAIR(5, vb.y) PAIR(6, vb.z) PAIR(7, vb.w)
#undef PAIR
    return yg;
}

// ---------------- Kernel 0: xh = (f16)x; zero qout --------------------------
// r23: no more xz/hpre zeroing (k_gemm now writes disjoint partial buffers
// with plain stores). k_xh is pure convert + tiny qout clear.
__global__ __launch_bounds__(256) void k_xh(
    const float* __restrict__ x, _Float16* __restrict__ xh,
    float* __restrict__ qout) {
    const int tid = blockIdx.x * 256 + threadIdx.x;
    const int i = tid * 8;
    float4 a = *(const float4*)(x + i);
    float4 b = *(const float4*)(x + i + 4);
    half8 o;
    o[0] = (_Float16)a.x; o[1] = (_Float16)a.y; o[2] = (_Float16)a.z; o[3] = (_Float16)a.w;
    o[4] = (_Float16)b.x; o[5] = (_Float16)b.y; o[6] = (_Float16)b.z; o[7] = (_Float16)b.w;
    *(half8*)(xh + i) = o;

    if (tid < 256) {
        const float4 z = {0.f, 0.f, 0.f, 0.f};
        *(float4*)(qout + tid * 4) = z;   // qout: 1024 floats
    }
}

// ---------------- Kernel 1: fused GEMM [hpre|xz1|xz2] = xh @ [Wh|Wz1|Wz2] ---
// grid (136, 2, 2) x 128 threads: 64-col strips, K-half split, ROW-half split.
// r23: each K-half writes its OWN partial buffer (offset part*64*ncols) with
// plain stores -- no atomics, no pre-zeroing. Consumers add the two parts
// ((a+b) identical to the old commutative 2-addend atomic result).
__global__ __launch_bounds__(128) void k_gemm(
    const _Float16* __restrict__ xh, const float* __restrict__ Wh,
    const float* __restrict__ Wz1, const float* __restrict__ Wz2,
    float* __restrict__ hpre, float* __restrict__ xz1,
    float* __restrict__ xz2) {
    const int s    = blockIdx.x;          // 64-col strip over [Wh|Wz1|Wz2]
    const int part = blockIdx.y;          // K-half
    const int k0   = part * 256;
    const int r0   = blockIdx.z * 32;     // row half: 0-31 or 32-63
    const int t    = threadIdx.x;
    const int l    = t & 63, w = t >> 6;
    const int hi   = l >> 5, l31 = l & 31;
    const int cbase = s * 64;

    const float* __restrict__ W;
    float* __restrict__ out;
    int ncols, ocol;
    if (s < 8)       { W = Wh;  out = hpre; ncols = 512;  ocol = cbase; }
    else if (s < 72) { W = Wz1; out = xz1;  ncols = 4096; ocol = cbase - 512; }
    else             { W = Wz2; out = xz2;  ncols = 4096; ocol = cbase - 4608; }
    out += (size_t)part * 64 * ncols;     // partial buffer for this K-half

    const int col = ocol + 32 * w + l31;

    const f32x16 CZ = {0.f, 0.f, 0.f, 0.f, 0.f, 0.f, 0.f, 0.f,
                       0.f, 0.f, 0.f, 0.f, 0.f, 0.f, 0.f, 0.f};
    f32x16 acc0 = CZ;   // rows r0 .. r0+31

    const _Float16* __restrict__ a0p = xh + (r0 + l31) * 512 + 8 * hi + k0;
    const float* __restrict__    wp  = W + (size_t)(k0 + 8 * hi) * ncols + col;

#pragma unroll 2
    for (int kk = 0; kk < 256; kk += 16) {
        half8 a0 = *(const half8*)(a0p + kk);
        const float* wk = wp + (size_t)kk * ncols;
        half8 bf;
#pragma unroll
        for (int j = 0; j < 8; ++j)
            bf[j] = (_Float16)wk[(size_t)j * ncols];
        acc0 = __builtin_amdgcn_mfma_f32_32x32x16_f16(a0, bf, acc0, 0, 0, 0);
    }
#pragma unroll
    for (int i = 0; i < 16; ++i) {
        const int m = (i & 3) + 8 * (i >> 2) + 4 * hi;
        out[(size_t)(r0 + m) * ncols + col] = acc0[i];
    }
}

// ---------------- Kernel 2: fused LN (blocks 0-63) + prep (blocks 64-1087) --
// r23: inputs are two-part partial buffers; add parts at read.
__global__ __launch_bounds__(256) void k_mid(
    const float* __restrict__ hpre, const float* __restrict__ bh,
    const float* __restrict__ ls, const float* __restrict__ lb,
    const float* __restrict__ xz1, const float* __restrict__ xz2,
    const float* __restrict__ Wz1, const float* __restrict__ Wz2,
    float* __restrict__ hout,
    _Float16* __restrict__ z1h, _Float16* __restrict__ z2h,
    _Float16* __restrict__ z2bh) {
    const int t  = threadIdx.x;
    const int l  = t & 63, wv = t >> 6;

    __shared__ float red[44 * 4];
    __shared__ float Ssum[44];

    if (blockIdx.x < 64) {
        // ---------------- LayerNorm path ----------------
        const int b = blockIdx.x;
        const float* __restrict__ hA = hpre;
        const float* __restrict__ hB = hpre + 64 * 512;
        float h0 = fmaxf((hA[b * 512 + t]       + hB[b * 512 + t])       + bh[t],       0.f);
        float h1 = fmaxf((hA[b * 512 + t + 256] + hB[b * 512 + t + 256]) + bh[t + 256], 0.f);
        float s = h0 + h1, ss = h0 * h0 + h1 * h1;
#pragma unroll
        for (int m = 1; m < 64; m <<= 1) {
            s  += __shfl_xor(s, m);
            ss += __shfl_xor(ss, m);
        }
        if (l == 0) { red[wv] = s; red[4 + wv] = ss; }
        __syncthreads();
        s  = red[0] + red[1] + red[2] + red[3];
        ss = red[4] + red[5] + red[6] + red[7];
        float mean = s * (1.0f / 512.0f);
        float var  = ss * (1.0f / 512.0f) - mean * mean;
        float rstd = rsqrtf(var + EPS);
        hout[b * 512 + t]       = (h0 - mean) * rstd * ls[t]       + lb[t];
        hout[b * 512 + t + 256] = (h1 - mean) * rstd * ls[t + 256] + lb[t + 256];
        return;
    }

    // ---------------- prep path: one block per row r ----------------
    const int r  = blockIdx.x - 64;
    const int br = r >> 4, a = r & 15;

    const float* __restrict__ x1a = xz1 + br * 4096;
    const float* __restrict__ x1b = xz1 + 64 * 4096 + br * 4096;
    const float* __restrict__ x2a = xz2 + br * 4096;
    const float* __restrict__ x2b = xz2 + 64 * 4096 + br * 4096;
    const float* __restrict__ w1r = Wz1 + (512 + a) * 4096;
    const float* __restrict__ w2r = Wz2 + (512 + a) * 4096;

    float pm[8], pg[36];
#pragma unroll
    for (int i = 0; i < 8; ++i) pm[i] = 0.f;
#pragma unroll
    for (int i = 0; i < 36; ++i) pg[i] = 0.f;

    half8 h2keep[2];
#pragma unroll
    for (int p = 0; p < 2; ++p) {
        const int d = t + p * 256;
        half8 h1, h2;
#pragma unroll
        for (int h = 0; h < 8; ++h) {
            float z1v = (x1a[h * 512 + d] + x1b[h * 512 + d]) + w1r[h * 512 + d];
            float z2v = (x2a[h * 512 + d] + x2b[h * 512 + d]) + w2r[h * 512 + d];
            h1[h] = (_Float16)z1v;
            h2[h] = (_Float16)z2v;
        }
        *(half8*)(z1h + ((size_t)r * 512 + d) * 8) = h1;
        h2keep[p] = h2;
        float zr[8];
#pragma unroll
        for (int h = 0; h < 8; ++h) zr[h] = (float)h1[h];
#pragma unroll
        for (int h = 0; h < 8; ++h) pm[h] += zr[h];
        int id = 0;
#pragma unroll
        for (int h = 0; h < 8; ++h)
#pragma unroll
            for (int h2_ = h; h2_ < 8; ++h2_) { pg[id] += zr[h] * zr[h2_]; ++id; }
    }

#pragma unroll
    for (int m = 1; m < 64; m <<= 1) {
#pragma unroll
        for (int i = 0; i < 8; ++i)  pm[i] += __shfl_xor(pm[i], m);
#pragma unroll
        for (int i = 0; i < 36; ++i) pg[i] += __shfl_xor(pg[i], m);
    }
    if (l == 0) {
#pragma unroll
        for (int i = 0; i < 8; ++i)  red[i * 4 + wv]       = pm[i];
#pragma unroll
        for (int i = 0; i < 36; ++i) red[(8 + i) * 4 + wv] = pg[i];
    }
    __syncthreads();
    if (t < 44) Ssum[t] = red[t * 4 + 0] + red[t * 4 + 1] + red[t * 4 + 2] + red[t * 4 + 3];
    __syncthreads();

#pragma unroll
    for (int p = 0; p < 2; ++p) {
        const int g = t + p * 256;
        float zv[8];
#pragma unroll
        for (int h = 0; h < 8; ++h) zv[h] = (float)h2keep[p][h];
        float mean = 0.f;
#pragma unroll
        for (int h = 0; h < 8; ++h) mean = fmaf(zv[h], Ssum[h], mean);
        mean *= (1.0f / 512.0f);
        float e2 = 0.f;
        int id = 0;
#pragma unroll
        for (int h = 0; h < 8; ++h)
#pragma unroll
            for (int h2_ = h; h2_ < 8; ++h2_) {
                float p2 = zv[h] * zv[h2_] * Ssum[8 + id];
                e2 += (h2_ == h) ? p2 : 2.0f * p2;
                ++id;
            }
        e2 *= (1.0f / 512.0f);
        float var  = e2 - mean * mean;
        float sd   = sqrtf(fmaxf(var, 0.f));
        float rstd = 1.0f / (sd + EPS);
        z2bh[r * 512 + g] = (_Float16)(-mean * rstd);   // bias (no scale factor)
        half8 hs;
#pragma unroll
        for (int h = 0; h < 8; ++h) hs[h] = (_Float16)(zv[h] * rstd);
        *(half8*)(z2h + ((size_t)r * 512 + g) * 8) = hs;
    }
}

// ---------------- Kernel 3: SWAPPED-operand MFMA bilinear + lane-local dot --
// EXACT r15/r18 shape (proven 47.4 us, VGPR=40, WRITE 2.1 MB). Failed
// perturbations: r9 (reg-array scratch), r11 (launch_bounds 8 spill),
// r16 (hoist/full-unroll remat), r19 (unroll 4 spill), r21 (prep fusion:
// occupancy loss > traffic gain). unroll 2 + per-iter conditional addressing
// at 2048 blocks is the verified optimum. FROZEN.
__global__ __launch_bounds__(256, 4) void k_main(
    const _Float16* __restrict__ z1h, const _Float16* __restrict__ z2h,
    const _Float16* __restrict__ z2bh, const float* __restrict__ hbuf,
    float* __restrict__ yout, float* __restrict__ qout) {
    const int bx = blockIdx.x;
    const int r  = bx >> 1, gh = bx & 1;
    const int br = r >> 4;
    const int t  = threadIdx.x;
    const int l  = t & 63, wv = t >> 6;
    const int hi = l >> 5, l31 = l & 31;

    __shared__ __align__(16) _Float16 z1t[513 * 8];   // [d][h]; row 512 = {1,0..}
    __shared__ __align__(16) unsigned int vp[256];    // packed (v[d0],v[d0+1]) crow order
    __shared__ float wq[4];

    // ---- stage z1 ----
#pragma unroll
    for (int p = 0; p < 2; ++p) {
        const int d = t + p * 256;
        *(half8*)(z1t + d * 8) = *(const half8*)(z1h + ((size_t)r * 512 + d) * 8);
    }
    if (t == 0) {
        half8 one = {};
        one[0] = (_Float16)1.0f;
        *(half8*)(z1t + 512 * 8) = one;
    }
    // ---- stage v pairs in crow order: vp[(m*2+h2)*8 + j] ----
    {
        const float* __restrict__ vrow = hbuf + br * 512;
        const int mm = t >> 4, h2 = (t >> 3) & 1, j = t & 7;
        const int d0 = mm * 32 + 2 * (j & 1) + 8 * (j >> 1) + 4 * h2;
        vp[t] = __builtin_bit_cast(unsigned int, cvt_pk(vrow[d0], vrow[d0 + 1]));
    }
    __syncthreads();

    // ---- B fragments: 2 n-tiles per wave (g = gh*256 + wv*64 + {0,32}) ----
    const size_t gb = (size_t)r * 512 + gh * 256 + wv * 64 + l31;
    half8 Bf0, Bf1;
    if (hi) {
        half8 z = {};
        Bf0 = z; Bf0[0] = z2bh[gb];
        Bf1 = z; Bf1[0] = z2bh[gb + 32];
    } else {
        Bf0 = *(const half8*)(z2h + gb * 8);
        Bf1 = *(const half8*)(z2h + (gb + 32) * 8);
    }

    const f32x16 CZ = {0.f, 0.f, 0.f, 0.f, 0.f, 0.f, 0.f, 0.f,
                       0.f, 0.f, 0.f, 0.f, 0.f, 0.f, 0.f, 0.f};
    float yg0 = 0.f, yg1 = 0.f;
#pragma unroll 2
    for (int m = 0; m < 16; ++m) {
        const int arow = hi ? 512 : (m * 32 + l31);
        const half8 Aa = *(const half8*)(z1t + arow * 8);
        const uint4 va = *(const uint4*)(vp + (m * 2 + hi) * 8);
        const uint4 vb = *(const uint4*)(vp + (m * 2 + hi) * 8 + 4);
        f32x16 D0 = __builtin_amdgcn_mfma_f32_32x32x16_f16(Aa, Bf0, CZ, 0, 0, 0);
        yg0 = tile_finish(D0, va, vb, yg0);
        f32x16 D1 = __builtin_amdgcn_mfma_f32_32x32x16_f16(Aa, Bf1, CZ, 0, 0, 0);
        yg1 = tile_finish(D1, va, vb, yg1);
    }

    // ---- combine the hi/lo half-sums of each g column (r13 fix) ----
    yg0 += __shfl_xor(yg0, 32);
    yg1 += __shfl_xor(yg1, 32);

    // ---- epilogue: y store from lo half; q via 2-addend atomicAdd ----
    const int gy = r * 512 + gh * 256 + wv * 64 + l31;
    if (!hi) {
        yout[gy]      = yg0;
        yout[gy + 32] = yg1;
    }
    float qacc = hi ? 0.f : (yg0 * yg0 + yg1 * yg1);
#pragma unroll
    for (int m = 1; m < 64; m <<= 1) qacc += __shfl_xor(qacc, m);
    if (l == 0) wq[wv] = qacc;
    __syncthreads();
    if (t == 0) atomicAdd(qout + r, (wq[0] + wq[1] + wq[2] + wq[3]) * (1.0f / 512.0f));
}

// ---------------------------------------------------------------------------
extern "C" void kernel_launch(void* const* d_in, const int* in_sizes, int n_in,
                              void* d_out, int out_size, void* d_ws, size_t ws_size,
                              hipStream_t stream) {
    const float* x   = (const float*)d_in[0];   // (64, 512)
    const float* Wh  = (const float*)d_in[1];   // (512, 512)
    const float* bh  = (const float*)d_in[2];   // (512,)
    const float* ls  = (const float*)d_in[3];   // (512,)
    const float* lb  = (const float*)d_in[4];   // (512,)
    const float* Wz1 = (const float*)d_in[5];   // (528, 4096)
    const float* Wz2 = (const float*)d_in[6];   // (528, 4096)

    float* out  = (float*)d_out;
    float* hout = out;                 // 64*512
    float* qout = out + 32768;         // 64*16
    float* yout = out + 33792;         // 1024*512

    // workspace layout (bytes); xz1/xz2/hpre are TWO-PART partial buffers
    char* ws = (char*)d_ws;
    float*     xz1  = (float*)(ws);                           // 2 MB (2 parts)
    float*     xz2  = (float*)(ws + (2u << 20));              // 2 MB (2 parts)
    float*     hpre = (float*)(ws + (4u << 20));              // 256 KB (2 parts)
    _Float16*  xh   = (_Float16*)(ws + (4u << 20) + 262144);  // 64 KB
    _Float16*  z2bh = (_Float16*)(ws + (4u << 20) + 327680);  // 1 MB
    _Float16*  z1h  = (_Float16*)(ws + (6u << 20));           // 8.4 MB
    _Float16*  z2h  = z1h + (size_t)1024 * 512 * 8;           // 8.4 MB

    k_xh  <<<16, 256, 0, stream>>>(x, xh, qout);
    k_gemm<<<dim3(136, 2, 2), 128, 0, stream>>>(xh, Wh, Wz1, Wz2, hpre, xz1, xz2);
    k_mid <<<1088, 256, 0, stream>>>(hpre, bh, ls, lb, xz1, xz2, Wz1, Wz2,
                                     hout, z1h, z2h, z2bh);
    k_main<<<2048, 256, 0, stream>>>(z1h, z2h, z2bh, hout, yout, qout);
}

// Round 24
// 74.846 us; speedup vs baseline: 1.0602x; 1.0284x over previous
//
#include <hip/hip_runtime.h>
#include <math.h>

#define EPS 1e-6f

typedef _Float16 half8 __attribute__((ext_vector_type(8)));
typedef _Float16 half2v __attribute__((ext_vector_type(2)));
typedef __fp16  fp16x2r __attribute__((ext_vector_type(2)));
typedef float f32x16 __attribute__((ext_vector_type(16)));

__device__ __forceinline__ half2v cvt_pk(float a, float b) {
    fp16x2r v = __builtin_amdgcn_cvt_pkrtz(a, b);
    return __builtin_bit_cast(half2v, v);
}

__device__ __forceinline__ float fdot2f(half2v a, half2v b, float c) {
#if __has_builtin(__builtin_amdgcn_fdot2)
    return __builtin_amdgcn_fdot2(__builtin_bit_cast(fp16x2r, a),
                                  __builtin_bit_cast(fp16x2r, b), c, false);
#else
    return fmaf((float)a[0], (float)b[0], fmaf((float)a[1], (float)b[1], c));
#endif
}

// tanh poly finish for one 32x32 D-tile (transposed layout: lane = one g col).
__device__ __forceinline__ float tile_finish(const f32x16& D, uint4 va, uint4 vb,
                                             float yg) {
    const half2v CLO = {(_Float16)-2.5f, (_Float16)-2.5f};
    const half2v CHI = {(_Float16) 2.5f, (_Float16) 2.5f};
    const half2v C0  = {(_Float16)0.98335470f, (_Float16)0.98335470f};
    const half2v C1  = {(_Float16)-0.24780080f, (_Float16)-0.24780080f};
    const half2v C2  = {(_Float16)0.04040730f, (_Float16)0.04040730f};
    const half2v C3  = {(_Float16)-0.00252110f, (_Float16)-0.00252110f};
#define PAIR(jj, word) {                                          \
        half2v tt = cvt_pk(D[2*jj], D[2*jj+1]);                   \
        tt = __builtin_elementwise_max(tt, CLO);                  \
        tt = __builtin_elementwise_min(tt, CHI);                  \
        half2v u  = tt * tt;                                      \
        half2v pp = C3 * u + C2;                                  \
        pp = pp * u + C1;                                         \
        pp = pp * u + C0;                                         \
        half2v wt = tt * pp;                                      \
        yg = fdot2f(wt, __builtin_bit_cast(half2v, word), yg); }
    PAIR(0, va.x) PAIR(1, va.y) PAIR(2, va.z) PAIR(3, va.w)
    PAIR(4, vb.x) PAIR(5, vb.y) PAIR(6, vb.z) PAIR(7, vb.w)
#undef PAIR
    return yg;
}

// ---------------- Kernel 1: fused GEMM [hpre|xz1|xz2] = x @ [Wh|Wz1|Wz2] ----
// grid (136, 2, 2) x 128 threads: 64-col strips, K-half split, ROW-half split.
// r24: A read straight from f32 x with in-register RNE casts (x is 128 KB,
// L2-resident) -- the k_xh dispatch is gone. Block (0,0,0) zeroes qout
// (k_main's q atomics run 2 dispatches later). Each K-half writes its OWN
// partial buffer with plain stores; consumers add parts (bitwise == the old
// commutative 2-addend atomic result).
__global__ __launch_bounds__(128) void k_gemm(
    const float* __restrict__ x, const float* __restrict__ Wh,
    const float* __restrict__ Wz1, const float* __restrict__ Wz2,
    float* __restrict__ hpre, float* __restrict__ xz1,
    float* __restrict__ xz2, float* __restrict__ qout) {
    const int s    = blockIdx.x;          // 64-col strip over [Wh|Wz1|Wz2]
    const int part = blockIdx.y;          // K-half
    const int k0   = part * 256;
    const int r0   = blockIdx.z * 32;     // row half: 0-31 or 32-63
    const int t    = threadIdx.x;
    const int l    = t & 63, w = t >> 6;
    const int hi   = l >> 5, l31 = l & 31;
    const int cbase = s * 64;

    if (blockIdx.x == 0 && blockIdx.y == 0 && blockIdx.z == 0) {
        const float4 z = {0.f, 0.f, 0.f, 0.f};
        *(float4*)(qout + t * 8)     = z;
        *(float4*)(qout + t * 8 + 4) = z;
    }

    const float* __restrict__ W;
    float* __restrict__ out;
    int ncols, ocol;
    if (s < 8)       { W = Wh;  out = hpre; ncols = 512;  ocol = cbase; }
    else if (s < 72) { W = Wz1; out = xz1;  ncols = 4096; ocol = cbase - 512; }
    else             { W = Wz2; out = xz2;  ncols = 4096; ocol = cbase - 4608; }
    out += (size_t)part * 64 * ncols;     // partial buffer for this K-half

    const int col = ocol + 32 * w + l31;

    const f32x16 CZ = {0.f, 0.f, 0.f, 0.f, 0.f, 0.f, 0.f, 0.f,
                       0.f, 0.f, 0.f, 0.f, 0.f, 0.f, 0.f, 0.f};
    f32x16 acc0 = CZ;   // rows r0 .. r0+31

    const float* __restrict__ a0f = x + (r0 + l31) * 512 + 8 * hi + k0;
    const float* __restrict__ wp  = W + (size_t)(k0 + 8 * hi) * ncols + col;

#pragma unroll 2
    for (int kk = 0; kk < 256; kk += 16) {
        float4 xa = *(const float4*)(a0f + kk);
        float4 xb = *(const float4*)(a0f + kk + 4);
        half8 a0;
        a0[0] = (_Float16)xa.x; a0[1] = (_Float16)xa.y;
        a0[2] = (_Float16)xa.z; a0[3] = (_Float16)xa.w;
        a0[4] = (_Float16)xb.x; a0[5] = (_Float16)xb.y;
        a0[6] = (_Float16)xb.z; a0[7] = (_Float16)xb.w;
        const float* wk = wp + (size_t)kk * ncols;
        half8 bf;
#pragma unroll
        for (int j = 0; j < 8; ++j)
            bf[j] = (_Float16)wk[(size_t)j * ncols];
        acc0 = __builtin_amdgcn_mfma_f32_32x32x16_f16(a0, bf, acc0, 0, 0, 0);
    }
#pragma unroll
    for (int i = 0; i < 16; ++i) {
        const int m = (i & 3) + 8 * (i >> 2) + 4 * hi;
        out[(size_t)(r0 + m) * ncols + col] = acc0[i];
    }
}

// ---------------- Kernel 2: fused LN (blocks 0-63) + prep (blocks 64-1087) --
// inputs are two-part partial buffers; add parts at read.
__global__ __launch_bounds__(256) void k_mid(
    const float* __restrict__ hpre, const float* __restrict__ bh,
    const float* __restrict__ ls, const float* __restrict__ lb,
    const float* __restrict__ xz1, const float* __restrict__ xz2,
    const float* __restrict__ Wz1, const float* __restrict__ Wz2,
    float* __restrict__ hout,
    _Float16* __restrict__ z1h, _Float16* __restrict__ z2h,
    _Float16* __restrict__ z2bh) {
    const int t  = threadIdx.x;
    const int l  = t & 63, wv = t >> 6;

    __shared__ float red[44 * 4];
    __shared__ float Ssum[44];

    if (blockIdx.x < 64) {
        // ---------------- LayerNorm path ----------------
        const int b = blockIdx.x;
        const float* __restrict__ hA = hpre;
        const float* __restrict__ hB = hpre + 64 * 512;
        float h0 = fmaxf((hA[b * 512 + t]       + hB[b * 512 + t])       + bh[t],       0.f);
        float h1 = fmaxf((hA[b * 512 + t + 256] + hB[b * 512 + t + 256]) + bh[t + 256], 0.f);
        float s = h0 + h1, ss = h0 * h0 + h1 * h1;
#pragma unroll
        for (int m = 1; m < 64; m <<= 1) {
            s  += __shfl_xor(s, m);
            ss += __shfl_xor(ss, m);
        }
        if (l == 0) { red[wv] = s; red[4 + wv] = ss; }
        __syncthreads();
        s  = red[0] + red[1] + red[2] + red[3];
        ss = red[4] + red[5] + red[6] + red[7];
        float mean = s * (1.0f / 512.0f);
        float var  = ss * (1.0f / 512.0f) - mean * mean;
        float rstd = rsqrtf(var + EPS);
        hout[b * 512 + t]       = (h0 - mean) * rstd * ls[t]       + lb[t];
        hout[b * 512 + t + 256] = (h1 - mean) * rstd * ls[t + 256] + lb[t + 256];
        return;
    }

    // ---------------- prep path: one block per row r ----------------
    const int r  = blockIdx.x - 64;
    const int br = r >> 4, a = r & 15;

    const float* __restrict__ x1a = xz1 + br * 4096;
    const float* __restrict__ x1b = xz1 + 64 * 4096 + br * 4096;
    const float* __restrict__ x2a = xz2 + br * 4096;
    const float* __restrict__ x2b = xz2 + 64 * 4096 + br * 4096;
    const float* __restrict__ w1r = Wz1 + (512 + a) * 4096;
    const float* __restrict__ w2r = Wz2 + (512 + a) * 4096;

    float pm[8], pg[36];
#pragma unroll
    for (int i = 0; i < 8; ++i) pm[i] = 0.f;
#pragma unroll
    for (int i = 0; i < 36; ++i) pg[i] = 0.f;

    half8 h2keep[2];
#pragma unroll
    for (int p = 0; p < 2; ++p) {
        const int d = t + p * 256;
        half8 h1, h2;
#pragma unroll
        for (int h = 0; h < 8; ++h) {
            float z1v = (x1a[h * 512 + d] + x1b[h * 512 + d]) + w1r[h * 512 + d];
            float z2v = (x2a[h * 512 + d] + x2b[h * 512 + d]) + w2r[h * 512 + d];
            h1[h] = (_Float16)z1v;
            h2[h] = (_Float16)z2v;
        }
        *(half8*)(z1h + ((size_t)r * 512 + d) * 8) = h1;
        h2keep[p] = h2;
        float zr[8];
#pragma unroll
        for (int h = 0; h < 8; ++h) zr[h] = (float)h1[h];
#pragma unroll
        for (int h = 0; h < 8; ++h) pm[h] += zr[h];
        int id = 0;
#pragma unroll
        for (int h = 0; h < 8; ++h)
#pragma unroll
            for (int h2_ = h; h2_ < 8; ++h2_) { pg[id] += zr[h] * zr[h2_]; ++id; }
    }

#pragma unroll
    for (int m = 1; m < 64; m <<= 1) {
#pragma unroll
        for (int i = 0; i < 8; ++i)  pm[i] += __shfl_xor(pm[i], m);
#pragma unroll
        for (int i = 0; i < 36; ++i) pg[i] += __shfl_xor(pg[i], m);
    }
    if (l == 0) {
#pragma unroll
        for (int i = 0; i < 8; ++i)  red[i * 4 + wv]       = pm[i];
#pragma unroll
        for (int i = 0; i < 36; ++i) red[(8 + i) * 4 + wv] = pg[i];
    }
    __syncthreads();
    if (t < 44) Ssum[t] = red[t * 4 + 0] + red[t * 4 + 1] + red[t * 4 + 2] + red[t * 4 + 3];
    __syncthreads();

#pragma unroll
    for (int p = 0; p < 2; ++p) {
        const int g = t + p * 256;
        float zv[8];
#pragma unroll
        for (int h = 0; h < 8; ++h) zv[h] = (float)h2keep[p][h];
        float mean = 0.f;
#pragma unroll
        for (int h = 0; h < 8; ++h) mean = fmaf(zv[h], Ssum[h], mean);
        mean *= (1.0f / 512.0f);
        float e2 = 0.f;
        int id = 0;
#pragma unroll
        for (int h = 0; h < 8; ++h)
#pragma unroll
            for (int h2_ = h; h2_ < 8; ++h2_) {
                float p2 = zv[h] * zv[h2_] * Ssum[8 + id];
                e2 += (h2_ == h) ? p2 : 2.0f * p2;
                ++id;
            }
        e2 *= (1.0f / 512.0f);
        float var  = e2 - mean * mean;
        float sd   = sqrtf(fmaxf(var, 0.f));
        float rstd = 1.0f / (sd + EPS);
        z2bh[r * 512 + g] = (_Float16)(-mean * rstd);   // bias (no scale factor)
        half8 hs;
#pragma unroll
        for (int h = 0; h < 8; ++h) hs[h] = (_Float16)(zv[h] * rstd);
        *(half8*)(z2h + ((size_t)r * 512 + g) * 8) = hs;
    }
}

// ---------------- Kernel 3: SWAPPED-operand MFMA bilinear + lane-local dot --
// EXACT r15/r18 shape (proven 47.4 us, VGPR=40, WRITE 2.1 MB). Failed
// perturbations: r9 (reg-array scratch), r11 (launch_bounds 8 spill),
// r16 (hoist/full-unroll remat), r19 (unroll 4 spill), r21 (prep fusion:
// occupancy loss > traffic gain). unroll 2 + per-iter conditional addressing
// at 2048 blocks is the verified optimum. FROZEN.
__global__ __launch_bounds__(256, 4) void k_main(
    const _Float16* __restrict__ z1h, const _Float16* __restrict__ z2h,
    const _Float16* __restrict__ z2bh, const float* __restrict__ hbuf,
    float* __restrict__ yout, float* __restrict__ qout) {
    const int bx = blockIdx.x;
    const int r  = bx >> 1, gh = bx & 1;
    const int br = r >> 4;
    const int t  = threadIdx.x;
    const int l  = t & 63, wv = t >> 6;
    const int hi = l >> 5, l31 = l & 31;

    __shared__ __align__(16) _Float16 z1t[513 * 8];   // [d][h]; row 512 = {1,0..}
    __shared__ __align__(16) unsigned int vp[256];    // packed (v[d0],v[d0+1]) crow order
    __shared__ float wq[4];

    // ---- stage z1 ----
#pragma unroll
    for (int p = 0; p < 2; ++p) {
        const int d = t + p * 256;
        *(half8*)(z1t + d * 8) = *(const half8*)(z1h + ((size_t)r * 512 + d) * 8);
    }
    if (t == 0) {
        half8 one = {};
        one[0] = (_Float16)1.0f;
        *(half8*)(z1t + 512 * 8) = one;
    }
    // ---- stage v pairs in crow order: vp[(m*2+h2)*8 + j] ----
    {
        const float* __restrict__ vrow = hbuf + br * 512;
        const int mm = t >> 4, h2 = (t >> 3) & 1, j = t & 7;
        const int d0 = mm * 32 + 2 * (j & 1) + 8 * (j >> 1) + 4 * h2;
        vp[t] = __builtin_bit_cast(unsigned int, cvt_pk(vrow[d0], vrow[d0 + 1]));
    }
    __syncthreads();

    // ---- B fragments: 2 n-tiles per wave (g = gh*256 + wv*64 + {0,32}) ----
    const size_t gb = (size_t)r * 512 + gh * 256 + wv * 64 + l31;
    half8 Bf0, Bf1;
    if (hi) {
        half8 z = {};
        Bf0 = z; Bf0[0] = z2bh[gb];
        Bf1 = z; Bf1[0] = z2bh[gb + 32];
    } else {
        Bf0 = *(const half8*)(z2h + gb * 8);
        Bf1 = *(const half8*)(z2h + (gb + 32) * 8);
    }

    const f32x16 CZ = {0.f, 0.f, 0.f, 0.f, 0.f, 0.f, 0.f, 0.f,
                       0.f, 0.f, 0.f, 0.f, 0.f, 0.f, 0.f, 0.f};
    float yg0 = 0.f, yg1 = 0.f;
#pragma unroll 2
    for (int m = 0; m < 16; ++m) {
        const int arow = hi ? 512 : (m * 32 + l31);
        const half8 Aa = *(const half8*)(z1t + arow * 8);
        const uint4 va = *(const uint4*)(vp + (m * 2 + hi) * 8);
        const uint4 vb = *(const uint4*)(vp + (m * 2 + hi) * 8 + 4);
        f32x16 D0 = __builtin_amdgcn_mfma_f32_32x32x16_f16(Aa, Bf0, CZ, 0, 0, 0);
        yg0 = tile_finish(D0, va, vb, yg0);
        f32x16 D1 = __builtin_amdgcn_mfma_f32_32x32x16_f16(Aa, Bf1, CZ, 0, 0, 0);
        yg1 = tile_finish(D1, va, vb, yg1);
    }

    // ---- combine the hi/lo half-sums of each g column (r13 fix) ----
    yg0 += __shfl_xor(yg0, 32);
    yg1 += __shfl_xor(yg1, 32);

    // ---- epilogue: y store from lo half; q via 2-addend atomicAdd ----
    const int gy = r * 512 + gh * 256 + wv * 64 + l31;
    if (!hi) {
        yout[gy]      = yg0;
        yout[gy + 32] = yg1;
    }
    float qacc = hi ? 0.f : (yg0 * yg0 + yg1 * yg1);
#pragma unroll
    for (int m = 1; m < 64; m <<= 1) qacc += __shfl_xor(qacc, m);
    if (l == 0) wq[wv] = qacc;
    __syncthreads();
    if (t == 0) atomicAdd(qout + r, (wq[0] + wq[1] + wq[2] + wq[3]) * (1.0f / 512.0f));
}

// ---------------------------------------------------------------------------
extern "C" void kernel_launch(void* const* d_in, const int* in_sizes, int n_in,
                              void* d_out, int out_size, void* d_ws, size_t ws_size,
                              hipStream_t stream) {
    const float* x   = (const float*)d_in[0];   // (64, 512)
    const float* Wh  = (const float*)d_in[1];   // (512, 512)
    const float* bh  = (const float*)d_in[2];   // (512,)
    const float* ls  = (const float*)d_in[3];   // (512,)
    const float* lb  = (const float*)d_in[4];   // (512,)
    const float* Wz1 = (const float*)d_in[5];   // (528, 4096)
    const float* Wz2 = (const float*)d_in[6];   // (528, 4096)

    float* out  = (float*)d_out;
    float* hout = out;                 // 64*512
    float* qout = out + 32768;         // 64*16
    float* yout = out + 33792;         // 1024*512

    // workspace layout (bytes); xz1/xz2/hpre are TWO-PART partial buffers
    char* ws = (char*)d_ws;
    float*     xz1  = (float*)(ws);                           // 2 MB (2 parts)
    float*     xz2  = (float*)(ws + (2u << 20));              // 2 MB (2 parts)
    float*     hpre = (float*)(ws + (4u << 20));              // 256 KB (2 parts)
    _Float16*  z2bh = (_Float16*)(ws + (4u << 20) + 327680);  // 1 MB
    _Float16*  z1h  = (_Float16*)(ws + (6u << 20));           // 8.4 MB
    _Float16*  z2h  = z1h + (size_t)1024 * 512 * 8;           // 8.4 MB

    k_gemm<<<dim3(136, 2, 2), 128, 0, stream>>>(x, Wh, Wz1, Wz2, hpre, xz1, xz2, qout);
    k_mid <<<1088, 256, 0, stream>>>(hpre, bh, ls, lb, xz1, xz2, Wz1, Wz2,
                                     hout, z1h, z2h, z2bh);
    k_main<<<2048, 256, 0, stream>>>(z1h, z2h, z2bh, hout, yout, qout);
}